// Round 2
// baseline (152.740 us; speedup 1.0000x reference)
//
#include <hip/hip_runtime.h>

#define N 4096
#define C 512
#define BM 128
#define BN 128
#define BK 64

typedef __attribute__((ext_vector_type(8))) short short8;   // 8 bf16 = 4 VGPRs (MFMA A/B frag)
typedef __attribute__((ext_vector_type(4))) float f32x4;    // MFMA C/D frag

__device__ __forceinline__ unsigned f2bf(float f) {
    union { float f; unsigned u; } v; v.f = f;
    return (v.u + 0x7fffu + ((v.u >> 16) & 1u)) >> 16;      // RNE fp32->bf16
}

// K1: per-position inverse norms over C, and zero the rowsum scratch.
__global__ __launch_bounds__(256) void norms_kernel(const float* __restrict__ x,
                                                    float* __restrict__ inv_norm,
                                                    float* __restrict__ rowsum) {
    __shared__ float red[256];
    int n0 = blockIdx.x * 64;
    int nl = threadIdx.x & 63;
    int cg = threadIdx.x >> 6;          // 0..3, each covers 128 channels
    int n  = n0 + nl;
    float s = 0.f;
    #pragma unroll 4
    for (int c = cg * 128; c < cg * 128 + 128; ++c) {
        float v = x[(size_t)c * N + n];
        s = fmaf(v, v, s);
    }
    red[threadIdx.x] = s;
    __syncthreads();
    if (threadIdx.x < 64) {
        float t = red[threadIdx.x] + red[threadIdx.x + 64] +
                  red[threadIdx.x + 128] + red[threadIdx.x + 192];
        inv_norm[n0 + threadIdx.x] = 1.0f / sqrtf(t);
        rowsum[n0 + threadIdx.x]   = 0.f;
    }
}

// K2: energy tile = (X^T X) tile via bf16 MFMA; epilogue: cosine scale, exp,
// store unnormalized exp to out, atomic per-row partial sums.
__global__ __launch_bounds__(256, 2) void gemm_kernel(const float* __restrict__ x,
                                                      const float* __restrict__ inv_norm,
                                                      float* __restrict__ rowsum,
                                                      float* __restrict__ out) {
    __shared__ __align__(16) unsigned short As[BM * BK];   // [m][k], XOR-swizzled
    __shared__ __align__(16) unsigned short Bs[BN * BK];

    const int tid  = threadIdx.x;
    const int lane = tid & 63;
    const int wid  = tid >> 6;
    const int wm   = (wid >> 1) * 64;    // wave row offset in tile
    const int wn   = (wid & 1) * 64;     // wave col offset in tile
    const int bm0  = blockIdx.y * BM;
    const int bn0  = blockIdx.x * BN;

    const int sm = tid & 127;            // staging: which row (n) this thread fills
    const int kq = tid >> 7;             // staging: k-octet group (0..1), 4 octets each

    f32x4 acc[4][4];
    #pragma unroll
    for (int i = 0; i < 4; ++i)
        #pragma unroll
        for (int j = 0; j < 4; ++j)
            acc[i][j] = (f32x4){0.f, 0.f, 0.f, 0.f};

    #pragma unroll 1
    for (int kk = 0; kk < C; kk += BK) {
        // ---- stage A tile: X[kk+k][bm0+m] -> As[m][k] (bf16, swizzled, b128 writes) ----
        {
            const float* src = x + (size_t)kk * N + bm0 + sm;
            #pragma unroll
            for (int i = 0; i < 4; ++i) {
                const int o = kq * 4 + i;        // k-octet, k = o*8 .. o*8+7
                float f[8];
                #pragma unroll
                for (int j = 0; j < 8; ++j) f[j] = src[(size_t)(o * 8 + j) * N];
                uint4 pk;
                pk.x = f2bf(f[0]) | (f2bf(f[1]) << 16);
                pk.y = f2bf(f[2]) | (f2bf(f[3]) << 16);
                pk.z = f2bf(f[4]) | (f2bf(f[5]) << 16);
                pk.w = f2bf(f[6]) | (f2bf(f[7]) << 16);
                const int byteoff = sm * 128 + ((o * 16) ^ ((sm & 7) << 4));
                *(uint4*)((char*)As + byteoff) = pk;
            }
        }
        // ---- stage B tile: X[kk+k][bn0+n] -> Bs[n][k] ----
        {
            const float* src = x + (size_t)kk * N + bn0 + sm;
            #pragma unroll
            for (int i = 0; i < 4; ++i) {
                const int o = kq * 4 + i;
                float f[8];
                #pragma unroll
                for (int j = 0; j < 8; ++j) f[j] = src[(size_t)(o * 8 + j) * N];
                uint4 pk;
                pk.x = f2bf(f[0]) | (f2bf(f[1]) << 16);
                pk.y = f2bf(f[2]) | (f2bf(f[3]) << 16);
                pk.z = f2bf(f[4]) | (f2bf(f[5]) << 16);
                pk.w = f2bf(f[6]) | (f2bf(f[7]) << 16);
                const int byteoff = sm * 128 + ((o * 16) ^ ((sm & 7) << 4));
                *(uint4*)((char*)Bs + byteoff) = pk;
            }
        }
        __syncthreads();

        // ---- MFMA: two k-halves of 32 ----
        #pragma unroll
        for (int kh = 0; kh < 2; ++kh) {
            short8 af[4], bfr[4];
            const int kfr = kh * 32 + (lane >> 4) * 8;  // frag k base for this lane
            #pragma unroll
            for (int i = 0; i < 4; ++i) {
                int rowa = wm + i * 16 + (lane & 15);
                af[i]  = *(const short8*)((const char*)As + rowa * 128 + ((kfr * 2) ^ ((rowa & 7) << 4)));
                int rowb = wn + i * 16 + (lane & 15);
                bfr[i] = *(const short8*)((const char*)Bs + rowb * 128 + ((kfr * 2) ^ ((rowb & 7) << 4)));
            }
            #pragma unroll
            for (int i = 0; i < 4; ++i)
                #pragma unroll
                for (int j = 0; j < 4; ++j)
                    acc[i][j] = __builtin_amdgcn_mfma_f32_16x16x32_bf16(af[i], bfr[j], acc[i][j], 0, 0, 0);
        }
        __syncthreads();
    }

    // ---- epilogue: cosine scale -> exp -> store + row partial sums ----
    float inmj[4];
    #pragma unroll
    for (int j = 0; j < 4; ++j)
        inmj[j] = inv_norm[bn0 + wn + j * 16 + (lane & 15)];

    #pragma unroll
    for (int mi = 0; mi < 4; ++mi) {
        const int rowbase = bm0 + wm + mi * 16 + (lane >> 4) * 4;
        float inmi[4];
        #pragma unroll
        for (int r = 0; r < 4; ++r) inmi[r] = inv_norm[rowbase + r];

        float rsum[4] = {0.f, 0.f, 0.f, 0.f};
        #pragma unroll
        for (int ni = 0; ni < 4; ++ni) {
            const int colg = bn0 + wn + ni * 16 + (lane & 15);
            #pragma unroll
            for (int r = 0; r < 4; ++r) {
                float e = __expf(acc[mi][ni][r] * inmi[r] * inmj[ni]);
                out[(size_t)(rowbase + r) * N + colg] = e;
                rsum[r] += e;
            }
        }
        #pragma unroll
        for (int r = 0; r < 4; ++r) {
            float p = rsum[r];
            p += __shfl_xor(p, 1);
            p += __shfl_xor(p, 2);
            p += __shfl_xor(p, 4);
            p += __shfl_xor(p, 8);
            if ((lane & 15) == 0) atomicAdd(&rowsum[rowbase + r], p);
        }
    }
}

// K3: normalize each row by its sum.
__global__ __launch_bounds__(256) void scale_kernel(float* __restrict__ out,
                                                    const float* __restrict__ rowsum) {
    const int row = blockIdx.x;
    const float inv = 1.0f / rowsum[row];
    f32x4* p = (f32x4*)(out + (size_t)row * N);
    #pragma unroll
    for (int i = threadIdx.x; i < N / 4; i += 256) {
        f32x4 v = p[i];
        v.x *= inv; v.y *= inv; v.z *= inv; v.w *= inv;
        p[i] = v;
    }
}

extern "C" void kernel_launch(void* const* d_in, const int* in_sizes, int n_in,
                              void* d_out, int out_size, void* d_ws, size_t ws_size,
                              hipStream_t stream) {
    const float* x = (const float*)d_in[0];
    float* out = (float*)d_out;
    float* inv_norm = (float*)d_ws;            // 4096 floats
    float* rowsum   = inv_norm + N;            // 4096 floats

    norms_kernel<<<64, 256, 0, stream>>>(x, inv_norm, rowsum);
    dim3 grid(N / BN, N / BM);
    gemm_kernel<<<grid, 256, 0, stream>>>(x, inv_norm, rowsum, out);
    scale_kernel<<<N, 256, 0, stream>>>(out, rowsum);
}

// Round 3
// 128.476 us; speedup vs baseline: 1.1889x; 1.1889x over previous
//
#include <hip/hip_runtime.h>

#define N 4096
#define C 512
#define BM 128
#define BN 128
#define BK 64

typedef __attribute__((ext_vector_type(8))) short short8;   // 8 bf16 (MFMA A/B frag)
typedef __attribute__((ext_vector_type(4))) float f32x4;    // MFMA C/D frag

__device__ __forceinline__ unsigned f2bf(float f) {
    union { float f; unsigned u; } v; v.f = f;
    return (v.u + 0x7fffu + ((v.u >> 16) & 1u)) >> 16;      // RNE fp32->bf16
}

__device__ __forceinline__ void gld_lds16(const void* g, void* l) {
    __builtin_amdgcn_global_load_lds(
        (const __attribute__((address_space(1))) unsigned int*)g,
        (__attribute__((address_space(3))) unsigned int*)l, 16, 0, 0);
}

// ---------------------------------------------------------------------------
// prep: fused fp32->bf16 convert + transpose (XT[n][c], c contiguous) + column
// norms (inv_norm) + zero rowsum. One block per 64-n panel, full C sweep.
__global__ __launch_bounds__(256) void prep_kernel(const float* __restrict__ x,
                                                   unsigned short* __restrict__ xt,
                                                   float* __restrict__ inv_norm,
                                                   float* __restrict__ rowsum) {
    __shared__ unsigned short tile[64 * 72];   // [c][n], stride 72 elems (144B) kills col-read conflicts
    __shared__ float red[16][64];
    const int t   = threadIdx.x;
    const int n0  = blockIdx.x * 64;
    const int cr0 = t >> 4;        // writer: c-row within 16-group
    const int nq  = t & 15;        // writer: n-quad
    const int nrd = t & 63;        // reader: n
    const int crd = t >> 6;        // reader: c-16-group (== wave id)
    float sq[4] = {0.f, 0.f, 0.f, 0.f};

    for (int cc = 0; cc < C; cc += 64) {
        #pragma unroll
        for (int p = 0; p < 4; ++p) {
            const int cl = p * 16 + cr0;
            const float4 v = *(const float4*)(x + (size_t)(cc + cl) * N + n0 + nq * 4);
            sq[0] = fmaf(v.x, v.x, sq[0]);
            sq[1] = fmaf(v.y, v.y, sq[1]);
            sq[2] = fmaf(v.z, v.z, sq[2]);
            sq[3] = fmaf(v.w, v.w, sq[3]);
            ushort4 b;
            b.x = (unsigned short)f2bf(v.x);
            b.y = (unsigned short)f2bf(v.y);
            b.z = (unsigned short)f2bf(v.z);
            b.w = (unsigned short)f2bf(v.w);
            *(ushort4*)(&tile[cl * 72 + nq * 4]) = b;
        }
        __syncthreads();
        {   // transpose out: each thread emits 16 consecutive c's (32B) for one n
            unsigned q[8];
            #pragma unroll
            for (int j = 0; j < 8; ++j) {
                unsigned lo = tile[(crd * 16 + 2 * j    ) * 72 + nrd];
                unsigned hi = tile[(crd * 16 + 2 * j + 1) * 72 + nrd];
                q[j] = lo | (hi << 16);
            }
            uint4* dst = (uint4*)(xt + (size_t)(n0 + nrd) * C + cc + crd * 16);
            dst[0] = make_uint4(q[0], q[1], q[2], q[3]);
            dst[1] = make_uint4(q[4], q[5], q[6], q[7]);
        }
        __syncthreads();
    }
    red[cr0][nq * 4 + 0] = sq[0];
    red[cr0][nq * 4 + 1] = sq[1];
    red[cr0][nq * 4 + 2] = sq[2];
    red[cr0][nq * 4 + 3] = sq[3];
    __syncthreads();
    if (t < 64) {
        float s = 0.f;
        #pragma unroll
        for (int r = 0; r < 16; ++r) s += red[r][t];
        inv_norm[n0 + t] = 1.0f / sqrtf(s);
        rowsum[n0 + t]   = 0.f;
    }
}

// ---------------------------------------------------------------------------
// gemm: energy tile via bf16 MFMA, staged with global_load_lds width-16.
// LDS logical layout: element (m,k) at byte m*128 + ((k*2) ^ ((m&7)<<4)).
// gload writes linearly; source address inverse-swizzled per lane (rule #21).
__global__ __launch_bounds__(256, 2) void gemm_kernel(const unsigned short* __restrict__ xt,
                                                      const float* __restrict__ inv_norm,
                                                      float* __restrict__ rowsum,
                                                      float* __restrict__ out) {
    __shared__ __align__(16) unsigned short As[BM * BK];
    __shared__ __align__(16) unsigned short Bs[BN * BK];

    const int tid  = threadIdx.x;
    const int lane = tid & 63;
    const int wid  = tid >> 6;
    const int wm   = (wid >> 1) * 64;
    const int wn   = (wid & 1) * 64;
    const int bm0  = blockIdx.y * BM;
    const int bn0  = blockIdx.x * BN;

    // staging: instruction i = wid*4+j writes LDS bytes [i*1024, i*1024+1024);
    // lane l covers m = i*8 + (l>>3), stored octet l&7  -> k-octet (l&7)^((l>>3)&7)
    const int mrow = lane >> 3;
    const int koct = (lane & 7) ^ (mrow & 7);
    const unsigned short* srcA = xt + (size_t)(bm0 + wid * 32 + mrow) * C + koct * 8;
    const unsigned short* srcB = xt + (size_t)(bn0 + wid * 32 + mrow) * C + koct * 8;

    f32x4 acc[4][4];
    #pragma unroll
    for (int i = 0; i < 4; ++i)
        #pragma unroll
        for (int j = 0; j < 4; ++j)
            acc[i][j] = (f32x4){0.f, 0.f, 0.f, 0.f};

    #pragma unroll
    for (int kk = 0; kk < C; kk += BK) {
        #pragma unroll
        for (int j = 0; j < 4; ++j)
            gld_lds16(srcA + (size_t)j * 8 * C + kk, As + (wid * 4 + j) * 512);
        #pragma unroll
        for (int j = 0; j < 4; ++j)
            gld_lds16(srcB + (size_t)j * 8 * C + kk, Bs + (wid * 4 + j) * 512);
        __syncthreads();

        #pragma unroll
        for (int kh = 0; kh < 2; ++kh) {
            short8 af[4], bfr[4];
            const int kfr = kh * 32 + (lane >> 4) * 8;
            #pragma unroll
            for (int i = 0; i < 4; ++i) {
                int rowa = wm + i * 16 + (lane & 15);
                af[i]  = *(const short8*)((const char*)As + rowa * 128 + ((kfr * 2) ^ ((rowa & 7) << 4)));
                int rowb = wn + i * 16 + (lane & 15);
                bfr[i] = *(const short8*)((const char*)Bs + rowb * 128 + ((kfr * 2) ^ ((rowb & 7) << 4)));
            }
            #pragma unroll
            for (int i = 0; i < 4; ++i)
                #pragma unroll
                for (int j = 0; j < 4; ++j)
                    acc[i][j] = __builtin_amdgcn_mfma_f32_16x16x32_bf16(af[i], bfr[j], acc[i][j], 0, 0, 0);
        }
        __syncthreads();
    }

    // epilogue: cosine scale -> exp -> store + per-row partial sums
    float inmj[4];
    #pragma unroll
    for (int j = 0; j < 4; ++j)
        inmj[j] = inv_norm[bn0 + wn + j * 16 + (lane & 15)];

    #pragma unroll
    for (int mi = 0; mi < 4; ++mi) {
        const int rowbase = bm0 + wm + mi * 16 + (lane >> 4) * 4;
        float inmi[4];
        #pragma unroll
        for (int r = 0; r < 4; ++r) inmi[r] = inv_norm[rowbase + r];

        float rsum[4] = {0.f, 0.f, 0.f, 0.f};
        #pragma unroll
        for (int ni = 0; ni < 4; ++ni) {
            const int colg = bn0 + wn + ni * 16 + (lane & 15);
            #pragma unroll
            for (int r = 0; r < 4; ++r) {
                float e = __expf(acc[mi][ni][r] * inmi[r] * inmj[ni]);
                out[(size_t)(rowbase + r) * N + colg] = e;
                rsum[r] += e;
            }
        }
        #pragma unroll
        for (int r = 0; r < 4; ++r) {
            float p = rsum[r];
            p += __shfl_xor(p, 1);
            p += __shfl_xor(p, 2);
            p += __shfl_xor(p, 4);
            p += __shfl_xor(p, 8);
            if ((lane & 15) == 0) atomicAdd(&rowsum[rowbase + r], p);
        }
    }
}

// ---------------------------------------------------------------------------
// fallback GEMM path (round-2 passing version) if ws can't hold XT
__global__ __launch_bounds__(256) void norms_kernel(const float* __restrict__ x,
                                                    float* __restrict__ inv_norm,
                                                    float* __restrict__ rowsum) {
    __shared__ float red[256];
    int n0 = blockIdx.x * 64;
    int nl = threadIdx.x & 63;
    int cg = threadIdx.x >> 6;
    int n  = n0 + nl;
    float s = 0.f;
    #pragma unroll 4
    for (int c = cg * 128; c < cg * 128 + 128; ++c) {
        float v = x[(size_t)c * N + n];
        s = fmaf(v, v, s);
    }
    red[threadIdx.x] = s;
    __syncthreads();
    if (threadIdx.x < 64) {
        float t = red[threadIdx.x] + red[threadIdx.x + 64] +
                  red[threadIdx.x + 128] + red[threadIdx.x + 192];
        inv_norm[n0 + threadIdx.x] = 1.0f / sqrtf(t);
        rowsum[n0 + threadIdx.x]   = 0.f;
    }
}

__global__ __launch_bounds__(256, 2) void gemm_fallback(const float* __restrict__ x,
                                                        const float* __restrict__ inv_norm,
                                                        float* __restrict__ rowsum,
                                                        float* __restrict__ out) {
    __shared__ __align__(16) unsigned short As[BM * BK];
    __shared__ __align__(16) unsigned short Bs[BN * BK];
    const int tid  = threadIdx.x;
    const int lane = tid & 63;
    const int wid  = tid >> 6;
    const int wm   = (wid >> 1) * 64;
    const int wn   = (wid & 1) * 64;
    const int bm0  = blockIdx.y * BM;
    const int bn0  = blockIdx.x * BN;
    const int sm = tid & 127;
    const int kq = tid >> 7;

    f32x4 acc[4][4];
    #pragma unroll
    for (int i = 0; i < 4; ++i)
        #pragma unroll
        for (int j = 0; j < 4; ++j)
            acc[i][j] = (f32x4){0.f, 0.f, 0.f, 0.f};

    #pragma unroll 1
    for (int kk = 0; kk < C; kk += BK) {
        {
            const float* src = x + (size_t)kk * N + bm0 + sm;
            #pragma unroll
            for (int i = 0; i < 4; ++i) {
                const int o = kq * 4 + i;
                float f[8];
                #pragma unroll
                for (int j = 0; j < 8; ++j) f[j] = src[(size_t)(o * 8 + j) * N];
                uint4 pk;
                pk.x = f2bf(f[0]) | (f2bf(f[1]) << 16);
                pk.y = f2bf(f[2]) | (f2bf(f[3]) << 16);
                pk.z = f2bf(f[4]) | (f2bf(f[5]) << 16);
                pk.w = f2bf(f[6]) | (f2bf(f[7]) << 16);
                const int byteoff = sm * 128 + ((o * 16) ^ ((sm & 7) << 4));
                *(uint4*)((char*)As + byteoff) = pk;
            }
        }
        {
            const float* src = x + (size_t)kk * N + bn0 + sm;
            #pragma unroll
            for (int i = 0; i < 4; ++i) {
                const int o = kq * 4 + i;
                float f[8];
                #pragma unroll
                for (int j = 0; j < 8; ++j) f[j] = src[(size_t)(o * 8 + j) * N];
                uint4 pk;
                pk.x = f2bf(f[0]) | (f2bf(f[1]) << 16);
                pk.y = f2bf(f[2]) | (f2bf(f[3]) << 16);
                pk.z = f2bf(f[4]) | (f2bf(f[5]) << 16);
                pk.w = f2bf(f[6]) | (f2bf(f[7]) << 16);
                const int byteoff = sm * 128 + ((o * 16) ^ ((sm & 7) << 4));
                *(uint4*)((char*)Bs + byteoff) = pk;
            }
        }
        __syncthreads();
        #pragma unroll
        for (int kh = 0; kh < 2; ++kh) {
            short8 af[4], bfr[4];
            const int kfr = kh * 32 + (lane >> 4) * 8;
            #pragma unroll
            for (int i = 0; i < 4; ++i) {
                int rowa = wm + i * 16 + (lane & 15);
                af[i]  = *(const short8*)((const char*)As + rowa * 128 + ((kfr * 2) ^ ((rowa & 7) << 4)));
                int rowb = wn + i * 16 + (lane & 15);
                bfr[i] = *(const short8*)((const char*)Bs + rowb * 128 + ((kfr * 2) ^ ((rowb & 7) << 4)));
            }
            #pragma unroll
            for (int i = 0; i < 4; ++i)
                #pragma unroll
                for (int j = 0; j < 4; ++j)
                    acc[i][j] = __builtin_amdgcn_mfma_f32_16x16x32_bf16(af[i], bfr[j], acc[i][j], 0, 0, 0);
        }
        __syncthreads();
    }

    float inmj[4];
    #pragma unroll
    for (int j = 0; j < 4; ++j)
        inmj[j] = inv_norm[bn0 + wn + j * 16 + (lane & 15)];
    #pragma unroll
    for (int mi = 0; mi < 4; ++mi) {
        const int rowbase = bm0 + wm + mi * 16 + (lane >> 4) * 4;
        float inmi[4];
        #pragma unroll
        for (int r = 0; r < 4; ++r) inmi[r] = inv_norm[rowbase + r];
        float rsum[4] = {0.f, 0.f, 0.f, 0.f};
        #pragma unroll
        for (int ni = 0; ni < 4; ++ni) {
            const int colg = bn0 + wn + ni * 16 + (lane & 15);
            #pragma unroll
            for (int r = 0; r < 4; ++r) {
                float e = __expf(acc[mi][ni][r] * inmi[r] * inmj[ni]);
                out[(size_t)(rowbase + r) * N + colg] = e;
                rsum[r] += e;
            }
        }
        #pragma unroll
        for (int r = 0; r < 4; ++r) {
            float p = rsum[r];
            p += __shfl_xor(p, 1);
            p += __shfl_xor(p, 2);
            p += __shfl_xor(p, 4);
            p += __shfl_xor(p, 8);
            if ((lane & 15) == 0) atomicAdd(&rowsum[rowbase + r], p);
        }
    }
}

// K3: normalize each row by its sum.
__global__ __launch_bounds__(256) void scale_kernel(float* __restrict__ out,
                                                    const float* __restrict__ rowsum) {
    const int row = blockIdx.x;
    const float inv = 1.0f / rowsum[row];
    f32x4* p = (f32x4*)(out + (size_t)row * N);
    #pragma unroll
    for (int i = threadIdx.x; i < N / 4; i += 256) {
        f32x4 v = p[i];
        v.x *= inv; v.y *= inv; v.z *= inv; v.w *= inv;
        p[i] = v;
    }
}

extern "C" void kernel_launch(void* const* d_in, const int* in_sizes, int n_in,
                              void* d_out, int out_size, void* d_ws, size_t ws_size,
                              hipStream_t stream) {
    const float* x = (const float*)d_in[0];
    float* out = (float*)d_out;
    float* inv_norm = (float*)d_ws;                      // N floats
    float* rowsum   = inv_norm + N;                      // N floats
    unsigned short* xt = (unsigned short*)(rowsum + N);  // N*C bf16 = 4 MB

    const size_t need = (size_t)2 * N * sizeof(float) + (size_t)N * C * sizeof(unsigned short);
    dim3 grid(N / BN, N / BM);
    if (ws_size >= need) {
        prep_kernel<<<64, 256, 0, stream>>>(x, xt, inv_norm, rowsum);
        gemm_kernel<<<grid, 256, 0, stream>>>(xt, inv_norm, rowsum, out);
    } else {
        norms_kernel<<<64, 256, 0, stream>>>(x, inv_norm, rowsum);
        gemm_fallback<<<grid, 256, 0, stream>>>(x, inv_norm, rowsum, out);
    }
    scale_kernel<<<N, 256, 0, stream>>>(out, rowsum);
}

// Round 7
// 128.069 us; speedup vs baseline: 1.1926x; 1.0032x over previous
//
#include <hip/hip_runtime.h>

#define N 4096
#define C 512
#define BM 128
#define BN 128
#define BK 64

typedef __attribute__((ext_vector_type(8))) short short8;   // 8 bf16 (MFMA A/B frag)
typedef __attribute__((ext_vector_type(4))) float f32x4;    // MFMA C/D frag

__device__ __forceinline__ unsigned f2bf(float f) {
    union { float f; unsigned u; } v; v.f = f;
    return (v.u + 0x7fffu + ((v.u >> 16) & 1u)) >> 16;      // RNE fp32->bf16
}

__device__ __forceinline__ void gld_lds16(const void* g, void* l) {
    __builtin_amdgcn_global_load_lds(
        (const __attribute__((address_space(1))) unsigned int*)g,
        (__attribute__((address_space(3))) unsigned int*)l, 16, 0, 0);
}

// ---------------------------------------------------------------------------
// prep v2: one block per 64n x 64c tile (grid 64x8 = 512 blocks).
// Fused fp32->bf16 convert + transpose into XT[n][c] + PARTIAL column sqsums.
__global__ __launch_bounds__(256) void prep_kernel(const float* __restrict__ x,
                                                   unsigned short* __restrict__ xt,
                                                   float* __restrict__ partial) {
    __shared__ unsigned short tile[64 * 72];   // [c][n], stride 72 elems kills col-read conflicts
    __shared__ float red[16][64];
    const int t   = threadIdx.x;
    const int n0  = blockIdx.x * 64;
    const int c0  = blockIdx.y * 64;
    const int cr0 = t >> 4;        // writer: c-row within 16-group (0..15)
    const int nq  = t & 15;        // writer: n-quad
    const int nrd = t & 63;        // reader: n
    const int crd = t >> 6;        // reader: c-16-group (== wave id)
    float sq[4] = {0.f, 0.f, 0.f, 0.f};

    #pragma unroll
    for (int p = 0; p < 4; ++p) {
        const int cl = p * 16 + cr0;
        const float4 v = *(const float4*)(x + (size_t)(c0 + cl) * N + n0 + nq * 4);
        sq[0] = fmaf(v.x, v.x, sq[0]);
        sq[1] = fmaf(v.y, v.y, sq[1]);
        sq[2] = fmaf(v.z, v.z, sq[2]);
        sq[3] = fmaf(v.w, v.w, sq[3]);
        ushort4 b;
        b.x = (unsigned short)f2bf(v.x);
        b.y = (unsigned short)f2bf(v.y);
        b.z = (unsigned short)f2bf(v.z);
        b.w = (unsigned short)f2bf(v.w);
        *(ushort4*)(&tile[cl * 72 + nq * 4]) = b;
    }
    red[cr0][nq * 4 + 0] = sq[0];
    red[cr0][nq * 4 + 1] = sq[1];
    red[cr0][nq * 4 + 2] = sq[2];
    red[cr0][nq * 4 + 3] = sq[3];
    __syncthreads();
    {   // transpose out: each thread emits 16 consecutive c's (32B) for one n
        unsigned q[8];
        #pragma unroll
        for (int j = 0; j < 8; ++j) {
            unsigned lo = tile[(crd * 16 + 2 * j    ) * 72 + nrd];
            unsigned hi = tile[(crd * 16 + 2 * j + 1) * 72 + nrd];
            q[j] = lo | (hi << 16);
        }
        uint4* dst = (uint4*)(xt + (size_t)(n0 + nrd) * C + c0 + crd * 16);
        dst[0] = make_uint4(q[0], q[1], q[2], q[3]);
        dst[1] = make_uint4(q[4], q[5], q[6], q[7]);
    }
    if (t < 64) {
        float s = 0.f;
        #pragma unroll
        for (int r = 0; r < 16; ++r) s += red[r][t];
        partial[blockIdx.y * N + n0 + t] = s;
    }
}

// finish: inv_norm from 8 partials; zero rowsum. 16 blocks x 256.
__global__ __launch_bounds__(256) void finish_kernel(const float* __restrict__ partial,
                                                     float* __restrict__ inv_norm,
                                                     float* __restrict__ rowsum) {
    const int n = blockIdx.x * 256 + threadIdx.x;
    float s = 0.f;
    #pragma unroll
    for (int j = 0; j < 8; ++j) s += partial[j * N + n];
    inv_norm[n] = 1.0f / sqrtf(s);
    rowsum[n]   = 0.f;
}

// ---------------------------------------------------------------------------
// gemm: energy tile via bf16 MFMA, staged with global_load_lds width-16.
// LDS logical layout: element (m,k) at byte m*128 + ((k*2) ^ ((m&7)<<4)).
// gload writes linearly; source address inverse-swizzled per lane (rule #21).
__global__ __launch_bounds__(256, 2) void gemm_kernel(const unsigned short* __restrict__ xt,
                                                      const float* __restrict__ inv_norm,
                                                      float* __restrict__ rowsum,
                                                      float* __restrict__ out) {
    __shared__ __align__(16) unsigned short As[BM * BK];
    __shared__ __align__(16) unsigned short Bs[BN * BK];

    const int tid  = threadIdx.x;
    const int lane = tid & 63;
    const int wid  = tid >> 6;
    const int wm   = (wid >> 1) * 64;
    const int wn   = (wid & 1) * 64;
    const int bm0  = blockIdx.y * BM;
    const int bn0  = blockIdx.x * BN;

    const int mrow = lane >> 3;
    const int koct = (lane & 7) ^ (mrow & 7);
    const unsigned short* srcA = xt + (size_t)(bm0 + wid * 32 + mrow) * C + koct * 8;
    const unsigned short* srcB = xt + (size_t)(bn0 + wid * 32 + mrow) * C + koct * 8;

    f32x4 acc[4][4];
    #pragma unroll
    for (int i = 0; i < 4; ++i)
        #pragma unroll
        for (int j = 0; j < 4; ++j)
            acc[i][j] = (f32x4){0.f, 0.f, 0.f, 0.f};

    #pragma unroll
    for (int kk = 0; kk < C; kk += BK) {
        #pragma unroll
        for (int j = 0; j < 4; ++j)
            gld_lds16(srcA + (size_t)j * 8 * C + kk, As + (wid * 4 + j) * 512);
        #pragma unroll
        for (int j = 0; j < 4; ++j)
            gld_lds16(srcB + (size_t)j * 8 * C + kk, Bs + (wid * 4 + j) * 512);
        __syncthreads();

        #pragma unroll
        for (int kh = 0; kh < 2; ++kh) {
            short8 af[4], bfr[4];
            const int kfr = kh * 32 + (lane >> 4) * 8;
            #pragma unroll
            for (int i = 0; i < 4; ++i) {
                int rowa = wm + i * 16 + (lane & 15);
                af[i]  = *(const short8*)((const char*)As + rowa * 128 + ((kfr * 2) ^ ((rowa & 7) << 4)));
                int rowb = wn + i * 16 + (lane & 15);
                bfr[i] = *(const short8*)((const char*)Bs + rowb * 128 + ((kfr * 2) ^ ((rowb & 7) << 4)));
            }
            #pragma unroll
            for (int i = 0; i < 4; ++i)
                #pragma unroll
                for (int j = 0; j < 4; ++j)
                    acc[i][j] = __builtin_amdgcn_mfma_f32_16x16x32_bf16(af[i], bfr[j], acc[i][j], 0, 0, 0);
        }
        __syncthreads();
    }

    // epilogue: cosine scale -> exp -> store + per-row partial sums
    float inmj[4];
    #pragma unroll
    for (int j = 0; j < 4; ++j)
        inmj[j] = inv_norm[bn0 + wn + j * 16 + (lane & 15)];

    #pragma unroll
    for (int mi = 0; mi < 4; ++mi) {
        const int rowbase = bm0 + wm + mi * 16 + (lane >> 4) * 4;
        float inmi[4];
        #pragma unroll
        for (int r = 0; r < 4; ++r) inmi[r] = inv_norm[rowbase + r];

        float rsum[4] = {0.f, 0.f, 0.f, 0.f};
        #pragma unroll
        for (int ni = 0; ni < 4; ++ni) {
            const int colg = bn0 + wn + ni * 16 + (lane & 15);
            #pragma unroll
            for (int r = 0; r < 4; ++r) {
                float e = __expf(acc[mi][ni][r] * inmi[r] * inmj[ni]);
                out[(size_t)(rowbase + r) * N + colg] = e;
                rsum[r] += e;
            }
        }
        #pragma unroll
        for (int r = 0; r < 4; ++r) {
            float p = rsum[r];
            p += __shfl_xor(p, 1);
            p += __shfl_xor(p, 2);
            p += __shfl_xor(p, 4);
            p += __shfl_xor(p, 8);
            if ((lane & 15) == 0) atomicAdd(&rowsum[rowbase + r], p);
        }
    }
}

// ---------------------------------------------------------------------------
// fallback path (round-2 passing version) if ws can't hold XT
__global__ __launch_bounds__(256) void norms_kernel(const float* __restrict__ x,
                                                    float* __restrict__ inv_norm,
                                                    float* __restrict__ rowsum) {
    __shared__ float red[256];
    int n0 = blockIdx.x * 64;
    int nl = threadIdx.x & 63;
    int cg = threadIdx.x >> 6;
    int n  = n0 + nl;
    float s = 0.f;
    #pragma unroll 4
    for (int c = cg * 128; c < cg * 128 + 128; ++c) {
        float v = x[(size_t)c * N + n];
        s = fmaf(v, v, s);
    }
    red[threadIdx.x] = s;
    __syncthreads();
    if (threadIdx.x < 64) {
        float t = red[threadIdx.x] + red[threadIdx.x + 64] +
                  red[threadIdx.x + 128] + red[threadIdx.x + 192];
        inv_norm[n0 + threadIdx.x] = 1.0f / sqrtf(t);
        rowsum[n0 + threadIdx.x]   = 0.f;
    }
}

__global__ __launch_bounds__(256, 2) void gemm_fallback(const float* __restrict__ x,
                                                        const float* __restrict__ inv_norm,
                                                        float* __restrict__ rowsum,
                                                        float* __restrict__ out) {
    __shared__ __align__(16) unsigned short As[BM * BK];
    __shared__ __align__(16) unsigned short Bs[BN * BK];
    const int tid  = threadIdx.x;
    const int lane = tid & 63;
    const int wid  = tid >> 6;
    const int wm   = (wid >> 1) * 64;
    const int wn   = (wid & 1) * 64;
    const int bm0  = blockIdx.y * BM;
    const int bn0  = blockIdx.x * BN;
    const int sm = tid & 127;
    const int kq = tid >> 7;

    f32x4 acc[4][4];
    #pragma unroll
    for (int i = 0; i < 4; ++i)
        #pragma unroll
        for (int j = 0; j < 4; ++j)
            acc[i][j] = (f32x4){0.f, 0.f, 0.f, 0.f};

    #pragma unroll 1
    for (int kk = 0; kk < C; kk += BK) {
        {
            const float* src = x + (size_t)kk * N + bm0 + sm;
            #pragma unroll
            for (int i = 0; i < 4; ++i) {
                const int o = kq * 4 + i;
                float f[8];
                #pragma unroll
                for (int j = 0; j < 8; ++j) f[j] = src[(size_t)(o * 8 + j) * N];
                uint4 pk;
                pk.x = f2bf(f[0]) | (f2bf(f[1]) << 16);
                pk.y = f2bf(f[2]) | (f2bf(f[3]) << 16);
                pk.z = f2bf(f[4]) | (f2bf(f[5]) << 16);
                pk.w = f2bf(f[6]) | (f2bf(f[7]) << 16);
                const int byteoff = sm * 128 + ((o * 16) ^ ((sm & 7) << 4));
                *(uint4*)((char*)As + byteoff) = pk;
            }
        }
        {
            const float* src = x + (size_t)kk * N + bn0 + sm;
            #pragma unroll
            for (int i = 0; i < 4; ++i) {
                const int o = kq * 4 + i;
                float f[8];
                #pragma unroll
                for (int j = 0; j < 8; ++j) f[j] = src[(size_t)(o * 8 + j) * N];
                uint4 pk;
                pk.x = f2bf(f[0]) | (f2bf(f[1]) << 16);
                pk.y = f2bf(f[2]) | (f2bf(f[3]) << 16);
                pk.z = f2bf(f[4]) | (f2bf(f[5]) << 16);
                pk.w = f2bf(f[6]) | (f2bf(f[7]) << 16);
                const int byteoff = sm * 128 + ((o * 16) ^ ((sm & 7) << 4));
                *(uint4*)((char*)Bs + byteoff) = pk;
            }
        }
        __syncthreads();
        #pragma unroll
        for (int kh = 0; kh < 2; ++kh) {
            short8 af[4], bfr[4];
            const int kfr = kh * 32 + (lane >> 4) * 8;
            #pragma unroll
            for (int i = 0; i < 4; ++i) {
                int rowa = wm + i * 16 + (lane & 15);
                af[i]  = *(const short8*)((const char*)As + rowa * 128 + ((kfr * 2) ^ ((rowa & 7) << 4)));
                int rowb = wn + i * 16 + (lane & 15);
                bfr[i] = *(const short8*)((const char*)Bs + rowb * 128 + ((kfr * 2) ^ ((rowb & 7) << 4)));
            }
            #pragma unroll
            for (int i = 0; i < 4; ++i)
                #pragma unroll
                for (int j = 0; j < 4; ++j)
                    acc[i][j] = __builtin_amdgcn_mfma_f32_16x16x32_bf16(af[i], bfr[j], acc[i][j], 0, 0, 0);
        }
        __syncthreads();
    }

    float inmj[4];
    #pragma unroll
    for (int j = 0; j < 4; ++j)
        inmj[j] = inv_norm[bn0 + wn + j * 16 + (lane & 15)];
    #pragma unroll
    for (int mi = 0; mi < 4; ++mi) {
        const int rowbase = bm0 + wm + mi * 16 + (lane >> 4) * 4;
        float inmi[4];
        #pragma unroll
        for (int r = 0; r < 4; ++r) inmi[r] = inv_norm[rowbase + r];
        float rsum[4] = {0.f, 0.f, 0.f, 0.f};
        #pragma unroll
        for (int ni = 0; ni < 4; ++ni) {
            const int colg = bn0 + wn + ni * 16 + (lane & 15);
            #pragma unroll
            for (int r = 0; r < 4; ++r) {
                float e = __expf(acc[mi][ni][r] * inmi[r] * inmj[ni]);
                out[(size_t)(rowbase + r) * N + colg] = e;
                rsum[r] += e;
            }
        }
        #pragma unroll
        for (int r = 0; r < 4; ++r) {
            float p = rsum[r];
            p += __shfl_xor(p, 1);
            p += __shfl_xor(p, 2);
            p += __shfl_xor(p, 4);
            p += __shfl_xor(p, 8);
            if ((lane & 15) == 0) atomicAdd(&rowsum[rowbase + r], p);
        }
    }
}

// K3: normalize each row by its sum.
__global__ __launch_bounds__(256) void scale_kernel(float* __restrict__ out,
                                                    const float* __restrict__ rowsum) {
    const int row = blockIdx.x;
    const float inv = 1.0f / rowsum[row];
    f32x4* p = (f32x4*)(out + (size_t)row * N);
    #pragma unroll
    for (int i = threadIdx.x; i < N / 4; i += 256) {
        f32x4 v = p[i];
        v.x *= inv; v.y *= inv; v.z *= inv; v.w *= inv;
        p[i] = v;
    }
}

extern "C" void kernel_launch(void* const* d_in, const int* in_sizes, int n_in,
                              void* d_out, int out_size, void* d_ws, size_t ws_size,
                              hipStream_t stream) {
    const float* x = (const float*)d_in[0];
    float* out = (float*)d_out;
    float* inv_norm = (float*)d_ws;                      // N floats
    float* rowsum   = inv_norm + N;                      // N floats
    float* partial  = rowsum + N;                        // 8*N floats
    unsigned short* xt = (unsigned short*)(partial + 8 * N);  // N*C bf16 = 4 MB

    const size_t need = (size_t)10 * N * sizeof(float) + (size_t)N * C * sizeof(unsigned short);
    dim3 grid(N / BN, N / BM);
    if (ws_size >= need) {
        dim3 pgrid(N / 64, C / 64);
        prep_kernel<<<pgrid, 256, 0, stream>>>(x, xt, partial);
        finish_kernel<<<N / 256, 256, 0, stream>>>(partial, inv_norm, rowsum);
        gemm_kernel<<<grid, 256, 0, stream>>>(xt, inv_norm, rowsum, out);
    } else {
        norms_kernel<<<64, 256, 0, stream>>>(x, inv_norm, rowsum);
        gemm_fallback<<<grid, 256, 0, stream>>>(x, inv_norm, rowsum, out);
    }
    scale_kernel<<<N, 256, 0, stream>>>(out, rowsum);
}

// Round 9
// 122.020 us; speedup vs baseline: 1.2518x; 1.0496x over previous
//
#include <hip/hip_runtime.h>

#define N 4096
#define C 512
#define BM 128
#define BN 128
#define BK 64

typedef __attribute__((ext_vector_type(8))) short short8;   // 8 bf16 (MFMA A/B frag)
typedef __attribute__((ext_vector_type(4))) float f32x4;    // MFMA C/D frag

__device__ __forceinline__ unsigned f2bf(float f) {
    union { float f; unsigned u; } v; v.f = f;
    return (v.u + 0x7fffu + ((v.u >> 16) & 1u)) >> 16;      // RNE fp32->bf16
}

__device__ __forceinline__ void gld_lds16(const void* g, void* l) {
    __builtin_amdgcn_global_load_lds(
        (const __attribute__((address_space(1))) unsigned int*)g,
        (__attribute__((address_space(3))) unsigned int*)l, 16, 0, 0);
}

// ---------------------------------------------------------------------------
// prep: one block per 64n x 64c tile (grid 64x8 = 512 blocks).
// Fused fp32->bf16 convert + transpose into XT[n][c] + PARTIAL column sqsums.
__global__ __launch_bounds__(256) void prep_kernel(const float* __restrict__ x,
                                                   unsigned short* __restrict__ xt,
                                                   float* __restrict__ partial) {
    __shared__ unsigned short tile[64 * 72];   // [c][n], stride 72 elems kills col-read conflicts
    __shared__ float red[16][64];
    const int t   = threadIdx.x;
    const int n0  = blockIdx.x * 64;
    const int c0  = blockIdx.y * 64;
    const int cr0 = t >> 4;        // writer: c-row within 16-group (0..15)
    const int nq  = t & 15;        // writer: n-quad
    const int nrd = t & 63;        // reader: n
    const int crd = t >> 6;        // reader: c-16-group (== wave id)
    float sq[4] = {0.f, 0.f, 0.f, 0.f};

    #pragma unroll
    for (int p = 0; p < 4; ++p) {
        const int cl = p * 16 + cr0;
        const float4 v = *(const float4*)(x + (size_t)(c0 + cl) * N + n0 + nq * 4);
        sq[0] = fmaf(v.x, v.x, sq[0]);
        sq[1] = fmaf(v.y, v.y, sq[1]);
        sq[2] = fmaf(v.z, v.z, sq[2]);
        sq[3] = fmaf(v.w, v.w, sq[3]);
        ushort4 b;
        b.x = (unsigned short)f2bf(v.x);
        b.y = (unsigned short)f2bf(v.y);
        b.z = (unsigned short)f2bf(v.z);
        b.w = (unsigned short)f2bf(v.w);
        *(ushort4*)(&tile[cl * 72 + nq * 4]) = b;
    }
    red[cr0][nq * 4 + 0] = sq[0];
    red[cr0][nq * 4 + 1] = sq[1];
    red[cr0][nq * 4 + 2] = sq[2];
    red[cr0][nq * 4 + 3] = sq[3];
    __syncthreads();
    {   // transpose out: each thread emits 16 consecutive c's (32B) for one n
        unsigned q[8];
        #pragma unroll
        for (int j = 0; j < 8; ++j) {
            unsigned lo = tile[(crd * 16 + 2 * j    ) * 72 + nrd];
            unsigned hi = tile[(crd * 16 + 2 * j + 1) * 72 + nrd];
            q[j] = lo | (hi << 16);
        }
        uint4* dst = (uint4*)(xt + (size_t)(n0 + nrd) * C + c0 + crd * 16);
        dst[0] = make_uint4(q[0], q[1], q[2], q[3]);
        dst[1] = make_uint4(q[4], q[5], q[6], q[7]);
    }
    if (t < 64) {
        float s = 0.f;
        #pragma unroll
        for (int r = 0; r < 16; ++r) s += red[r][t];
        partial[blockIdx.y * N + n0 + t] = s;
    }
}

// finish: inv_norm from 8 partials; zero rowsum. 16 blocks x 256.
__global__ __launch_bounds__(256) void finish_kernel(const float* __restrict__ partial,
                                                     float* __restrict__ inv_norm,
                                                     float* __restrict__ rowsum) {
    const int n = blockIdx.x * 256 + threadIdx.x;
    float s = 0.f;
    #pragma unroll
    for (int j = 0; j < 8; ++j) s += partial[j * N + n];
    inv_norm[n] = 1.0f / sqrtf(s);
    rowsum[n]   = 0.f;
}

// ---------------------------------------------------------------------------
// gemm: energy tile via bf16 MFMA, staged with global_load_lds width-16.
// Epilogue stores UNNORMALIZED exp as bf16 to ws (halves epilogue write
// traffic); fp32 rowsum accumulation unchanged.
__global__ __launch_bounds__(256, 2) void gemm_kernel(const unsigned short* __restrict__ xt,
                                                      const float* __restrict__ inv_norm,
                                                      float* __restrict__ rowsum,
                                                      unsigned short* __restrict__ expb) {
    __shared__ __align__(16) unsigned short As[BM * BK];
    __shared__ __align__(16) unsigned short Bs[BN * BK];

    const int tid  = threadIdx.x;
    const int lane = tid & 63;
    const int wid  = tid >> 6;
    const int wm   = (wid >> 1) * 64;
    const int wn   = (wid & 1) * 64;
    const int bm0  = blockIdx.y * BM;
    const int bn0  = blockIdx.x * BN;

    const int mrow = lane >> 3;
    const int koct = (lane & 7) ^ (mrow & 7);
    const unsigned short* srcA = xt + (size_t)(bm0 + wid * 32 + mrow) * C + koct * 8;
    const unsigned short* srcB = xt + (size_t)(bn0 + wid * 32 + mrow) * C + koct * 8;

    f32x4 acc[4][4];
    #pragma unroll
    for (int i = 0; i < 4; ++i)
        #pragma unroll
        for (int j = 0; j < 4; ++j)
            acc[i][j] = (f32x4){0.f, 0.f, 0.f, 0.f};

    #pragma unroll
    for (int kk = 0; kk < C; kk += BK) {
        #pragma unroll
        for (int j = 0; j < 4; ++j)
            gld_lds16(srcA + (size_t)j * 8 * C + kk, As + (wid * 4 + j) * 512);
        #pragma unroll
        for (int j = 0; j < 4; ++j)
            gld_lds16(srcB + (size_t)j * 8 * C + kk, Bs + (wid * 4 + j) * 512);
        __syncthreads();

        #pragma unroll
        for (int kh = 0; kh < 2; ++kh) {
            short8 af[4], bfr[4];
            const int kfr = kh * 32 + (lane >> 4) * 8;
            #pragma unroll
            for (int i = 0; i < 4; ++i) {
                int rowa = wm + i * 16 + (lane & 15);
                af[i]  = *(const short8*)((const char*)As + rowa * 128 + ((kfr * 2) ^ ((rowa & 7) << 4)));
                int rowb = wn + i * 16 + (lane & 15);
                bfr[i] = *(const short8*)((const char*)Bs + rowb * 128 + ((kfr * 2) ^ ((rowb & 7) << 4)));
            }
            #pragma unroll
            for (int i = 0; i < 4; ++i)
                #pragma unroll
                for (int j = 0; j < 4; ++j)
                    acc[i][j] = __builtin_amdgcn_mfma_f32_16x16x32_bf16(af[i], bfr[j], acc[i][j], 0, 0, 0);
        }
        __syncthreads();
    }

    // epilogue: cosine scale -> exp -> bf16 store + per-row partial sums
    float inmj[4];
    #pragma unroll
    for (int j = 0; j < 4; ++j)
        inmj[j] = inv_norm[bn0 + wn + j * 16 + (lane & 15)];

    #pragma unroll
    for (int mi = 0; mi < 4; ++mi) {
        const int rowbase = bm0 + wm + mi * 16 + (lane >> 4) * 4;
        float inmi[4];
        #pragma unroll
        for (int r = 0; r < 4; ++r) inmi[r] = inv_norm[rowbase + r];

        float rsum[4] = {0.f, 0.f, 0.f, 0.f};
        #pragma unroll
        for (int ni = 0; ni < 4; ++ni) {
            const int colg = bn0 + wn + ni * 16 + (lane & 15);
            #pragma unroll
            for (int r = 0; r < 4; ++r) {
                float e = __expf(acc[mi][ni][r] * inmi[r] * inmj[ni]);
                expb[(size_t)(rowbase + r) * N + colg] = (unsigned short)f2bf(e);
                rsum[r] += e;
            }
        }
        #pragma unroll
        for (int r = 0; r < 4; ++r) {
            float p = rsum[r];
            p += __shfl_xor(p, 1);
            p += __shfl_xor(p, 2);
            p += __shfl_xor(p, 4);
            p += __shfl_xor(p, 8);
            if ((lane & 15) == 0) atomicAdd(&rowsum[rowbase + r], p);
        }
    }
}

// scale v2: read bf16 exp from ws, write normalized fp32 to out.
__global__ __launch_bounds__(256) void scale_bf_kernel(const unsigned short* __restrict__ expb,
                                                       const float* __restrict__ rowsum,
                                                       float* __restrict__ out) {
    const int row = blockIdx.x;
    const float inv = 1.0f / rowsum[row];
    const uint4* src = (const uint4*)(expb + (size_t)row * N);
    float4* dst = (float4*)(out + (size_t)row * N);
    #pragma unroll
    for (int i = threadIdx.x; i < N / 8; i += 256) {
        uint4 v = src[i];   // 8 bf16
        float4 o0, o1;
        o0.x = __uint_as_float(v.x << 16)         * inv;
        o0.y = __uint_as_float(v.x & 0xffff0000u) * inv;
        o0.z = __uint_as_float(v.y << 16)         * inv;
        o0.w = __uint_as_float(v.y & 0xffff0000u) * inv;
        o1.x = __uint_as_float(v.z << 16)         * inv;
        o1.y = __uint_as_float(v.z & 0xffff0000u) * inv;
        o1.z = __uint_as_float(v.w << 16)         * inv;
        o1.w = __uint_as_float(v.w & 0xffff0000u) * inv;
        dst[2 * i]     = o0;
        dst[2 * i + 1] = o1;
    }
}

// ---------------------------------------------------------------------------
// mid path (round-7 exact): fp32 exp direct to out + fp32 scale
__global__ __launch_bounds__(256, 2) void gemm_f32(const unsigned short* __restrict__ xt,
                                                   const float* __restrict__ inv_norm,
                                                   float* __restrict__ rowsum,
                                                   float* __restrict__ out) {
    __shared__ __align__(16) unsigned short As[BM * BK];
    __shared__ __align__(16) unsigned short Bs[BN * BK];
    const int tid  = threadIdx.x;
    const int lane = tid & 63;
    const int wid  = tid >> 6;
    const int wm   = (wid >> 1) * 64;
    const int wn   = (wid & 1) * 64;
    const int bm0  = blockIdx.y * BM;
    const int bn0  = blockIdx.x * BN;
    const int mrow = lane >> 3;
    const int koct = (lane & 7) ^ (mrow & 7);
    const unsigned short* srcA = xt + (size_t)(bm0 + wid * 32 + mrow) * C + koct * 8;
    const unsigned short* srcB = xt + (size_t)(bn0 + wid * 32 + mrow) * C + koct * 8;

    f32x4 acc[4][4];
    #pragma unroll
    for (int i = 0; i < 4; ++i)
        #pragma unroll
        for (int j = 0; j < 4; ++j)
            acc[i][j] = (f32x4){0.f, 0.f, 0.f, 0.f};

    #pragma unroll
    for (int kk = 0; kk < C; kk += BK) {
        #pragma unroll
        for (int j = 0; j < 4; ++j)
            gld_lds16(srcA + (size_t)j * 8 * C + kk, As + (wid * 4 + j) * 512);
        #pragma unroll
        for (int j = 0; j < 4; ++j)
            gld_lds16(srcB + (size_t)j * 8 * C + kk, Bs + (wid * 4 + j) * 512);
        __syncthreads();
        #pragma unroll
        for (int kh = 0; kh < 2; ++kh) {
            short8 af[4], bfr[4];
            const int kfr = kh * 32 + (lane >> 4) * 8;
            #pragma unroll
            for (int i = 0; i < 4; ++i) {
                int rowa = wm + i * 16 + (lane & 15);
                af[i]  = *(const short8*)((const char*)As + rowa * 128 + ((kfr * 2) ^ ((rowa & 7) << 4)));
                int rowb = wn + i * 16 + (lane & 15);
                bfr[i] = *(const short8*)((const char*)Bs + rowb * 128 + ((kfr * 2) ^ ((rowb & 7) << 4)));
            }
            #pragma unroll
            for (int i = 0; i < 4; ++i)
                #pragma unroll
                for (int j = 0; j < 4; ++j)
                    acc[i][j] = __builtin_amdgcn_mfma_f32_16x16x32_bf16(af[i], bfr[j], acc[i][j], 0, 0, 0);
        }
        __syncthreads();
    }

    float inmj[4];
    #pragma unroll
    for (int j = 0; j < 4; ++j)
        inmj[j] = inv_norm[bn0 + wn + j * 16 + (lane & 15)];
    #pragma unroll
    for (int mi = 0; mi < 4; ++mi) {
        const int rowbase = bm0 + wm + mi * 16 + (lane >> 4) * 4;
        float inmi[4];
        #pragma unroll
        for (int r = 0; r < 4; ++r) inmi[r] = inv_norm[rowbase + r];
        float rsum[4] = {0.f, 0.f, 0.f, 0.f};
        #pragma unroll
        for (int ni = 0; ni < 4; ++ni) {
            const int colg = bn0 + wn + ni * 16 + (lane & 15);
            #pragma unroll
            for (int r = 0; r < 4; ++r) {
                float e = __expf(acc[mi][ni][r] * inmi[r] * inmj[ni]);
                out[(size_t)(rowbase + r) * N + colg] = e;
                rsum[r] += e;
            }
        }
        #pragma unroll
        for (int r = 0; r < 4; ++r) {
            float p = rsum[r];
            p += __shfl_xor(p, 1);
            p += __shfl_xor(p, 2);
            p += __shfl_xor(p, 4);
            p += __shfl_xor(p, 8);
            if ((lane & 15) == 0) atomicAdd(&rowsum[rowbase + r], p);
        }
    }
}

__global__ __launch_bounds__(256) void scale_kernel(float* __restrict__ out,
                                                    const float* __restrict__ rowsum) {
    const int row = blockIdx.x;
    const float inv = 1.0f / rowsum[row];
    f32x4* p = (f32x4*)(out + (size_t)row * N);
    #pragma unroll
    for (int i = threadIdx.x; i < N / 4; i += 256) {
        f32x4 v = p[i];
        v.x *= inv; v.y *= inv; v.z *= inv; v.w *= inv;
        p[i] = v;
    }
}

extern "C" void kernel_launch(void* const* d_in, const int* in_sizes, int n_in,
                              void* d_out, int out_size, void* d_ws, size_t ws_size,
                              hipStream_t stream) {
    const float* x = (const float*)d_in[0];
    float* out = (float*)d_out;
    float* inv_norm = (float*)d_ws;                      // N floats
    float* rowsum   = inv_norm + N;                      // N floats
    float* partial  = rowsum + N;                        // 8*N floats
    unsigned short* xt   = (unsigned short*)(partial + 8 * N);   // N*C bf16 = 4 MB
    unsigned short* expb = xt + (size_t)N * C;                   // N*N bf16 = 32 MB

    const size_t need_xt   = (size_t)10 * N * sizeof(float) + (size_t)N * C * sizeof(unsigned short);
    const size_t need_full = need_xt + (size_t)N * N * sizeof(unsigned short);
    dim3 grid(N / BN, N / BM);
    dim3 pgrid(N / 64, C / 64);

    if (ws_size >= need_full) {
        prep_kernel<<<pgrid, 256, 0, stream>>>(x, xt, partial);
        finish_kernel<<<N / 256, 256, 0, stream>>>(partial, inv_norm, rowsum);
        gemm_kernel<<<grid, 256, 0, stream>>>(xt, inv_norm, rowsum, expb);
        scale_bf_kernel<<<N, 256, 0, stream>>>(expb, rowsum, out);
    } else if (ws_size >= need_xt) {
        prep_kernel<<<pgrid, 256, 0, stream>>>(x, xt, partial);
        finish_kernel<<<N / 256, 256, 0, stream>>>(partial, inv_norm, rowsum);
        gemm_f32<<<grid, 256, 0, stream>>>(xt, inv_norm, rowsum, out);
        scale_kernel<<<N, 256, 0, stream>>>(out, rowsum);
    }
}